// Round 1
// baseline (807.475 us; speedup 1.0000x reference)
//
#include <hip/hip_runtime.h>

// GRU: B=4096, T=512, I=32, H=32, head -> y[B]
// One half-wave (32 lanes) per batch element; lane j owns hidden unit j.
// Weights for rows {j, 32+j, 64+j} of W_ih and W_hh held in 192 VGPRs.
// Per timestep: x-row + h-vector broadcast through LDS (write 1, read as
// float4 broadcasts), 192 FMAs per lane, gate math, h update.

#define TSTEPS 512

__global__ __launch_bounds__(256, 2)
void gru_fused_kernel(const float* __restrict__ x,
                      const float* __restrict__ W_ih,
                      const float* __restrict__ W_hh,
                      const float* __restrict__ b_ih,
                      const float* __restrict__ b_hh,
                      const float* __restrict__ w_head,
                      const float* __restrict__ b_head,
                      float* __restrict__ y)
{
    const int tid = threadIdx.x;
    const int hw  = tid >> 5;    // half-wave id in block: 0..7
    const int j   = tid & 31;    // hidden unit index
    const int b   = blockIdx.x * 8 + hw;

    // per-halfwave LDS region: [0..31] = x row, [32..63] = h vector
    __shared__ float sh[8 * 64];
    float* xs = &sh[hw * 64];
    float* hs = xs + 32;

    // ---- load weights into registers (one-time, amortized over 512 steps)
    float wr[32], wz[32], wn[32], ur[32], uz[32], un[32];
#pragma unroll
    for (int k = 0; k < 32; ++k) {
        wr[k] = W_ih[(j)      * 32 + k];
        wz[k] = W_ih[(32 + j) * 32 + k];
        wn[k] = W_ih[(64 + j) * 32 + k];
        ur[k] = W_hh[(j)      * 32 + k];
        uz[k] = W_hh[(32 + j) * 32 + k];
        un[k] = W_hh[(64 + j) * 32 + k];
    }
    const float br  = b_ih[j]      + b_hh[j];        // reset-gate bias (combined)
    const float bz  = b_ih[32 + j] + b_hh[32 + j];   // update-gate bias (combined)
    const float bni = b_ih[64 + j];                  // new-gate input bias
    const float bnh = b_hh[64 + j];                  // new-gate hidden bias (inside r*)

    float h = 0.0f;
    const float* xp = x + ((size_t)b * TSTEPS) * 32 + j;

    for (int t = 0; t < TSTEPS; ++t) {
        const float xv = xp[(size_t)t * 32];  // coalesced: 32 consecutive lanes
        xs[j] = xv;
        hs[j] = h;
        // same-wave LDS write->read: compiler inserts lgkmcnt wait (memory dep)

        float ar = br, az = bz, an = bni, ah = bnh;
        const float4* x4 = (const float4*)xs;
        const float4* h4 = (const float4*)hs;
#pragma unroll
        for (int q = 0; q < 8; ++q) {
            const float4 xq = x4[q];   // broadcast read, conflict-free
            const float4 hq = h4[q];
            ar = fmaf(wr[4*q+0], xq.x, ar); ar = fmaf(wr[4*q+1], xq.y, ar);
            ar = fmaf(wr[4*q+2], xq.z, ar); ar = fmaf(wr[4*q+3], xq.w, ar);
            az = fmaf(wz[4*q+0], xq.x, az); az = fmaf(wz[4*q+1], xq.y, az);
            az = fmaf(wz[4*q+2], xq.z, az); az = fmaf(wz[4*q+3], xq.w, az);
            an = fmaf(wn[4*q+0], xq.x, an); an = fmaf(wn[4*q+1], xq.y, an);
            an = fmaf(wn[4*q+2], xq.z, an); an = fmaf(wn[4*q+3], xq.w, an);
            ar = fmaf(ur[4*q+0], hq.x, ar); ar = fmaf(ur[4*q+1], hq.y, ar);
            ar = fmaf(ur[4*q+2], hq.z, ar); ar = fmaf(ur[4*q+3], hq.w, ar);
            az = fmaf(uz[4*q+0], hq.x, az); az = fmaf(uz[4*q+1], hq.y, az);
            az = fmaf(uz[4*q+2], hq.z, az); az = fmaf(uz[4*q+3], hq.w, az);
            ah = fmaf(un[4*q+0], hq.x, ah); ah = fmaf(un[4*q+1], hq.y, ah);
            ah = fmaf(un[4*q+2], hq.z, ah); ah = fmaf(un[4*q+3], hq.w, ah);
        }

        // gates
        const float r  = 1.0f / (1.0f + __expf(-ar));
        const float z  = 1.0f / (1.0f + __expf(-az));
        const float nv = an + r * ah;
        const float e  = __expf(2.0f * nv);
        const float n  = 1.0f - 2.0f / (e + 1.0f);   // tanh(nv), saturates correctly
        h = n + z * (h - n);
    }

    // ---- head: y[b] = sum_j h_j * w_head[j] + b_head
    float acc = h * w_head[j];
#pragma unroll
    for (int m = 16; m >= 1; m >>= 1)
        acc += __shfl_xor(acc, m, 32);
    if (j == 0)
        y[b] = acc + b_head[0];
}

extern "C" void kernel_launch(void* const* d_in, const int* in_sizes, int n_in,
                              void* d_out, int out_size, void* d_ws, size_t ws_size,
                              hipStream_t stream) {
    const float* x      = (const float*)d_in[0];
    const float* W_ih   = (const float*)d_in[1];
    const float* W_hh   = (const float*)d_in[2];
    const float* b_ih   = (const float*)d_in[3];
    const float* b_hh   = (const float*)d_in[4];
    const float* w_head = (const float*)d_in[5];
    const float* b_head = (const float*)d_in[6];
    float* y = (float*)d_out;

    const int B = 4096;
    dim3 grid(B / 8), block(256);
    gru_fused_kernel<<<grid, block, 0, stream>>>(x, W_ih, W_hh, b_ih, b_hh,
                                                 w_head, b_head, y);
}